// Round 8
// baseline (191.007 us; speedup 1.0000x reference)
//
#include <hip/hip_runtime.h>
#include <math.h>

#define N_VOX 32768
#define N_EMB 8192
#define DIM 64
#define NCHUNK 8
#define CODES_PER_CHUNK (N_EMB / NCHUNK)       // 1024
#define TILES_PER_CHUNK (CODES_PER_CHUNK / 32) // 32
#define NTILES (N_EMB / 32)                    // 256
#define TILE_BYTES 8192                        // bh[4x1KB] | bl[4x1KB]
#define CHUNK_BYTES (TILES_PER_CHUNK * TILE_BYTES)

typedef _Float16 half8 __attribute__((ext_vector_type(8)));
typedef float floatx4 __attribute__((ext_vector_type(4)));

#define FP16_MIN_NORMAL 6.1035156e-5f
#define LO_SCALE 2048.0f

// -------- kernel A: fused esq + B-fragment stream build (validated R9-R12) ---
// 256 thr/tile (thread = one (o,lane) slice). UNCHANGED layout:
// element (code n, k) lives at tile byte 512*(k>>3) + 16*n (+4096 for bl).
// c0arr[code] = -1024*esq.
__global__ __launch_bounds__(256) void cbprep_kernel(const float* __restrict__ cb,
                                                     char* __restrict__ stream,
                                                     float* __restrict__ c0arr) {
    __shared__ float red[256];
    int tid  = threadIdx.x;                      // 0..255
    int l    = tid & 63;
    int o    = tid >> 6;                         // K-chunk 0..3
    int m    = l & 31;
    int tile = blockIdx.x;                       // 0..255
    char* tbase = stream + (size_t)tile * TILE_BYTES;
    int code = tile * 32 + m;
    int kg   = l >> 5;

    const float* p = cb + (size_t)code * DIM + o * 16 + kg * 8;
    float ss = 0.f;
    half8 h, lo;
    #pragma unroll
    for (int j = 0; j < 8; ++j) {
        float x = p[j];
        ss = fmaf(x, x, ss);
        _Float16 hi = (_Float16)x;
        float hf = (float)hi;
        if (fabsf(hf) < FP16_MIN_NORMAL) { hi = (_Float16)0.f; hf = 0.f; }
        h[j]  = hi;
        lo[j] = (_Float16)((x - hf) * LO_SCALE);
    }
    *(half8*)(tbase +        o * 1024 + l * 16) = h;
    *(half8*)(tbase + 4096 + o * 1024 + l * 16) = lo;

    red[tid] = ss;
    __syncthreads();
    if (tid < 32) {                              // tid == m here
        float s = 0.f;
        #pragma unroll
        for (int q = 0; q < 8; ++q) s += red[tid + q * 32];
        c0arr[tile * 32 + tid] = -1024.0f * s;
    }
}

// -------- kernel B: MFMA argmin scan — 16x16x32 + register B double-buffer ---
// R8: R7 structure (8 waves/512thr, 32 rows/wave, 4 LDS buffers, 16x16x32
// with 4 independent MFMA chains) + REGISTER double-buffering of the
// B-fragments: at iter t, while the MFMA cluster consumes tile t's
// fragments (register set CUR), the 8 ds_read_b128 + 2 c0 reads for tile
// t+1 are issued into set NXT. R7's PMC showed per-tile wall =~ LDS-queue
// time (870cyc/CU) + MFMA time (930cyc/SIMD) SERIALIZED (post-barrier read
// burst); this overlaps them. Visibility: wait tightened to vmcnt(1)
// (own stages <= t+1 retired; all waves ditto before the shared barrier =>
// tile t+1 LDS-visible), vmcnt(0) for t>=30. Overwrite hazard: stage t+3
// (issued after barrier t) hits buf[(t-1)&3], last read at iter t-2 —
// >=1 barrier separation. Sets ping-pong via 2x-unrolled loop with NAMED
// sets (no runtime-indexed register arrays). Mappings/math/tie-break
// identical to R7 (validated): A/B idx=l&15, k=(l>>4)*8+j; C/D col=l&15,
// row=4*(l>>4)+reg; acc = 2048*(dot - esq/2); max, tie -> lower id.
__global__ __launch_bounds__(512) void scan_kernel(const float* __restrict__ z,
                                                   const char* __restrict__ stream,
                                                   const float* __restrict__ c0arr,
                                                   float* __restrict__ cand_val,
                                                   int* __restrict__ cand_idx) {
    __shared__ __align__(16) char lds[4 * TILE_BYTES + CODES_PER_CHUNK * 4];
    float* c0_lds = (float*)(lds + 4 * TILE_BYTES);
    int tid   = threadIdx.x;
    int l     = tid & 63;
    int w     = tid >> 6;                        // wave 0..7
    int chunk = blockIdx.x & (NCHUNK - 1);
    int rg    = blockIdx.x >> 3;                 // 0..127, 256 rows per block
    int lr    = l & 15;                          // A row / B col within group
    int lq    = l >> 4;                          // quarter: k-octet / C row-quad
    int rowBase = rg * 256 + w * 32;             // wave's 32 rows

    // A fragments per (rowgroup r, khalf h): zh, zl = 2048*res, zhs = 2048*zh
    half8 zh[2][2], zl[2][2], zhs[2][2];
    #pragma unroll
    for (int r = 0; r < 2; ++r) {
        #pragma unroll
        for (int h = 0; h < 2; ++h) {
            const float* p = z + (size_t)(rowBase + r * 16 + lr) * DIM + h * 32 + lq * 8;
            #pragma unroll
            for (int j = 0; j < 8; ++j) {
                float x = p[j];
                _Float16 hi = (_Float16)x;
                float hf = (float)hi;
                if (fabsf(hf) < FP16_MIN_NORMAL) { hi = (_Float16)0.f; hf = 0.f; }
                zh[r][h][j] = hi;
                zl[r][h][j] = (_Float16)((x - hf) * LO_SCALE);
            }
            zhs[r][h] = zh[r][h] * (_Float16)2048.0f;
        }
    }

    const char*  sbase = stream + (size_t)chunk * CHUNK_BYTES;
    const float* c0p   = c0arr + chunk * CODES_PER_CHUNK;

    // best/bt position p = r*8 + c*4 + i  (row = rowBase+r*16+4*lq+i,
    // col-in-tile = c*16+lr)
    float best[16];
    int   bt[16];
    #pragma unroll
    for (int i = 0; i < 16; ++i) { best[i] = -3.4e38f; bt[i] = 0; }

    struct BF {                                   // one tile's B fragments
        half8 h00, h10, h01, h11, l00, l10, l01, l11;
        float ca, cb;                             // c0 for colgroup 0/1
    };
    BF fA, fB;

    // stage one 8KB tile: wave w issues seg w (1KB, lane l -> +l*16)
#define STAGE(gt, lb)                                                              \
    do {                                                                           \
        const char* _g = (gt) + w * 1024 + l * 16;                                 \
        char*       _d = (lb) + w * 1024 + l * 16;                                 \
        __builtin_amdgcn_global_load_lds(                                          \
            (const __attribute__((address_space(1))) void*)_g,                     \
            (__attribute__((address_space(3))) void*)_d, 16, 0, 0);                \
    } while (0)

#define LOADB(B, lb, tt)                                                           \
    do {                                                                           \
        const char* bp_ = (lb) + 512 * lq + 16 * lr;                               \
        B.h00 = *(const half8*)(bp_ +    0);                                       \
        B.h10 = *(const half8*)(bp_ +  256);                                       \
        B.h01 = *(const half8*)(bp_ + 2048);                                       \
        B.h11 = *(const half8*)(bp_ + 2304);                                       \
        B.l00 = *(const half8*)(bp_ + 4096);                                       \
        B.l10 = *(const half8*)(bp_ + 4352);                                       \
        B.l01 = *(const half8*)(bp_ + 6144);                                       \
        B.l11 = *(const half8*)(bp_ + 6400);                                       \
        B.ca  = c0_lds[(tt) * 32 + lr];                                            \
        B.cb  = c0_lds[(tt) * 32 + 16 + lr];                                       \
    } while (0)

#define COMPUTE(B, t)                                                              \
    do {                                                                           \
        floatx4 a00 = {B.ca, B.ca, B.ca, B.ca};                                    \
        floatx4 a01 = {B.cb, B.cb, B.cb, B.cb};                                    \
        floatx4 a10 = {B.ca, B.ca, B.ca, B.ca};                                    \
        floatx4 a11 = {B.cb, B.cb, B.cb, B.cb};                                    \
        __builtin_amdgcn_s_setprio(1);                                             \
        a00 = __builtin_amdgcn_mfma_f32_16x16x32_f16(zhs[0][0], B.h00, a00, 0, 0, 0); \
        a01 = __builtin_amdgcn_mfma_f32_16x16x32_f16(zhs[0][0], B.h10, a01, 0, 0, 0); \
        a10 = __builtin_amdgcn_mfma_f32_16x16x32_f16(zhs[1][0], B.h00, a10, 0, 0, 0); \
        a11 = __builtin_amdgcn_mfma_f32_16x16x32_f16(zhs[1][0], B.h10, a11, 0, 0, 0); \
        a00 = __builtin_amdgcn_mfma_f32_16x16x32_f16(zl[0][0],  B.h00, a00, 0, 0, 0); \
        a01 = __builtin_amdgcn_mfma_f32_16x16x32_f16(zl[0][0],  B.h10, a01, 0, 0, 0); \
        a10 = __builtin_amdgcn_mfma_f32_16x16x32_f16(zl[1][0],  B.h00, a10, 0, 0, 0); \
        a11 = __builtin_amdgcn_mfma_f32_16x16x32_f16(zl[1][0],  B.h10, a11, 0, 0, 0); \
        a00 = __builtin_amdgcn_mfma_f32_16x16x32_f16(zh[0][0],  B.l00, a00, 0, 0, 0); \
        a01 = __builtin_amdgcn_mfma_f32_16x16x32_f16(zh[0][0],  B.l10, a01, 0, 0, 0); \
        a10 = __builtin_amdgcn_mfma_f32_16x16x32_f16(zh[1][0],  B.l00, a10, 0, 0, 0); \
        a11 = __builtin_amdgcn_mfma_f32_16x16x32_f16(zh[1][0],  B.l10, a11, 0, 0, 0); \
        a00 = __builtin_amdgcn_mfma_f32_16x16x32_f16(zhs[0][1], B.h01, a00, 0, 0, 0); \
        a01 = __builtin_amdgcn_mfma_f32_16x16x32_f16(zhs[0][1], B.h11, a01, 0, 0, 0); \
        a10 = __builtin_amdgcn_mfma_f32_16x16x32_f16(zhs[1][1], B.h01, a10, 0, 0, 0); \
        a11 = __builtin_amdgcn_mfma_f32_16x16x32_f16(zhs[1][1], B.h11, a11, 0, 0, 0); \
        a00 = __builtin_amdgcn_mfma_f32_16x16x32_f16(zl[0][1],  B.h01, a00, 0, 0, 0); \
        a01 = __builtin_amdgcn_mfma_f32_16x16x32_f16(zl[0][1],  B.h11, a01, 0, 0, 0); \
        a10 = __builtin_amdgcn_mfma_f32_16x16x32_f16(zl[1][1],  B.h01, a10, 0, 0, 0); \
        a11 = __builtin_amdgcn_mfma_f32_16x16x32_f16(zl[1][1],  B.h11, a11, 0, 0, 0); \
        a00 = __builtin_amdgcn_mfma_f32_16x16x32_f16(zh[0][1],  B.l01, a00, 0, 0, 0); \
        a01 = __builtin_amdgcn_mfma_f32_16x16x32_f16(zh[0][1],  B.l11, a01, 0, 0, 0); \
        a10 = __builtin_amdgcn_mfma_f32_16x16x32_f16(zh[1][1],  B.l01, a10, 0, 0, 0); \
        a11 = __builtin_amdgcn_mfma_f32_16x16x32_f16(zh[1][1],  B.l11, a11, 0, 0, 0); \
        __builtin_amdgcn_s_setprio(0);                                             \
        _Pragma("unroll")                                                          \
        for (int i = 0; i < 4; ++i) {                                              \
            if (a00[i] > best[ 0 + i]) { best[ 0 + i] = a00[i]; bt[ 0 + i] = (t); } \
            if (a01[i] > best[ 4 + i]) { best[ 4 + i] = a01[i]; bt[ 4 + i] = (t); } \
            if (a10[i] > best[ 8 + i]) { best[ 8 + i] = a10[i]; bt[ 8 + i] = (t); } \
            if (a11[i] > best[12 + i]) { best[12 + i] = a11[i]; bt[12 + i] = (t); } \
        }                                                                          \
    } while (0)

    // BODY(t): barrier makes tile t+1 visible; stage t+3; prefetch t+1 into
    // NXT while computing t from CUR.
#define BODY(t, CUR, NXT)                                                          \
    do {                                                                           \
        if ((t) < TILES_PER_CHUNK - 2)                                             \
            asm volatile("s_waitcnt vmcnt(1)" ::: "memory");                       \
        else                                                                       \
            asm volatile("s_waitcnt vmcnt(0)" ::: "memory");                       \
        __builtin_amdgcn_s_barrier();                                              \
        asm volatile("" ::: "memory");                                             \
        if ((t) + 3 < TILES_PER_CHUNK)                                             \
            STAGE(sbase + (size_t)((t) + 3) * TILE_BYTES,                          \
                  lds + (((t) + 3) & 3) * TILE_BYTES);                             \
        if ((t) + 1 < TILES_PER_CHUNK)                                             \
            LOADB(NXT, lds + (((t) + 1) & 3) * TILE_BYTES, (t) + 1);               \
        COMPUTE(CUR, (t));                                                         \
    } while (0)

    // prologue: stage tiles 0..2 into bufs 0..2, fill c0 LDS, make tile 0
    // visible (vmcnt(2): own stage-0 retired, all waves ditto + barrier),
    // then preload tile 0 into set A.
    STAGE(sbase,                          lds);
    STAGE(sbase + (size_t)TILE_BYTES,     lds + TILE_BYTES);
    STAGE(sbase + 2 * (size_t)TILE_BYTES, lds + 2 * TILE_BYTES);
    c0_lds[tid]       = c0p[tid];
    c0_lds[tid + 512] = c0p[tid + 512];
    asm volatile("s_waitcnt vmcnt(2)" ::: "memory");
    __syncthreads();                             // tile 0 + c0 visible
    LOADB(fA, lds, 0);

    for (int tp = 0; tp < TILES_PER_CHUNK / 2; ++tp) {
        int t0 = tp * 2;
        BODY(t0,     fA, fB);
        BODY(t0 + 1, fB, fA);
    }
#undef BODY
#undef COMPUTE
#undef LOADB
#undef STAGE

    // Epilogue: in-lane colgroup merge, then 4-step shuffle argmax over the
    // 16 cols (lane bits 0..3). Tie -> lower within-chunk id (tournament on
    // (v desc, id asc) — order-independent, same semantics as validated).
    #pragma unroll
    for (int r = 0; r < 2; ++r) {
        #pragma unroll
        for (int i = 0; i < 4; ++i) {
            float v0 = best[r * 8 + i];     int id0 = bt[r * 8 + i] * 32 + lr;
            float v1 = best[r * 8 + 4 + i]; int id1 = bt[r * 8 + 4 + i] * 32 + 16 + lr;
            float v = v0; int id = id0;
            if (v1 > v || (v1 == v && id1 < id)) { v = v1; id = id1; }
            #pragma unroll
            for (int off = 1; off < 16; off <<= 1) {
                float ov = __shfl_xor(v, off, 64);
                int   oi = __shfl_xor(id, off, 64);
                if (ov > v || (ov == v && oi < id)) { v = ov; id = oi; }
            }
            if (lr == 0) {
                int row = rowBase + r * 16 + 4 * lq + i;
                cand_val[chunk * N_VOX + row] = v;
                cand_idx[chunk * N_VOX + row] = chunk * CODES_PER_CHUNK + id;
            }
        }
    }
}

// -------- kernel C: pick max stored score + gather (no re-score) -------------
// 8 lanes per row: lane c reads chunk c's (val, idx); width-8 shuffle argmax
// (tie -> lower id) — identical ordering semantics to scan's within-chunk
// reduce, so cross-chunk pick is consistent with the validated pipeline.
__global__ __launch_bounds__(256) void finalize_kernel(const float* __restrict__ z,
                                                       const float* __restrict__ cb,
                                                       const float* __restrict__ cand_val,
                                                       const int* __restrict__ cand_idx,
                                                       float* __restrict__ out,
                                                       float* __restrict__ partials) {
    int g    = blockIdx.x * 256 + threadIdx.x;
    int row  = g >> 3;
    int c    = g & 7;                  // chunk / candidate 0..7

    float v  = cand_val[c * N_VOX + row];
    int   id = cand_idx[c * N_VOX + row];
    #pragma unroll
    for (int off = 1; off < 8; off <<= 1) {
        float ov = __shfl_xor(v, off, 8);
        int   oi = __shfl_xor(id, off, 8);
        if (ov > v || (ov == v && oi < id)) { v = ov; id = oi; }
    }
    // all 8 lanes hold the winning id for this row

    if (c == 0)
        out[(size_t)N_VOX * DIM + 2 + row] = (float)id;

    // cooperative gather+write: lane handles elements [c*8, c*8+8)
    const float4* zp = (const float4*)(z  + (size_t)row * DIM + c * 8);
    const float4* qp = (const float4*)(cb + (size_t)id  * DIM + c * 8);
    float4*       op = (float4*)(out + (size_t)row * DIM + c * 8);
    float ss = 0.f;
    #pragma unroll
    for (int d = 0; d < 2; ++d) {
        float4 zt = zp[d], qt = qp[d];
        float dx = qt.x - zt.x, dy = qt.y - zt.y;
        float dz = qt.z - zt.z, dw = qt.w - zt.w;
        float4 o;
        o.x = zt.x + dx; o.y = zt.y + dy;   // mirrors reference z + (q - z)
        o.z = zt.z + dz; o.w = zt.w + dw;
        op[d] = o;
        ss += dx*dx + dy*dy + dz*dz + dw*dw;
    }

    __shared__ float red[256];
    red[threadIdx.x] = ss;
    __syncthreads();
    #pragma unroll
    for (int s = 128; s > 0; s >>= 1) {
        if (threadIdx.x < s) red[threadIdx.x] += red[threadIdx.x + s];
        __syncthreads();
    }
    if (threadIdx.x == 0) partials[blockIdx.x] = red[0];
}

// -------- kernel D: reduce 1024 partials -> both losses --------
__global__ __launch_bounds__(256) void loss_kernel(const float* __restrict__ partials,
                                                   float* __restrict__ out) {
    __shared__ float red[256];
    red[threadIdx.x] = (partials[threadIdx.x]       + partials[threadIdx.x + 256])
                     + (partials[threadIdx.x + 512] + partials[threadIdx.x + 768]);
    __syncthreads();
    #pragma unroll
    for (int st = 128; st > 0; st >>= 1) {
        if (threadIdx.x < st) red[threadIdx.x] += red[threadIdx.x + st];
        __syncthreads();
    }
    if (threadIdx.x == 0) {
        float mean = red[0] / (float)((size_t)N_VOX * DIM);
        out[(size_t)N_VOX * DIM + 0] = mean;
        out[(size_t)N_VOX * DIM + 1] = mean;
    }
}

extern "C" void kernel_launch(void* const* d_in, const int* in_sizes, int n_in,
                              void* d_out, int out_size, void* d_ws, size_t ws_size,
                              hipStream_t stream) {
    const float* z  = (const float*)d_in[0];   // [32768, 64]
    const float* cb = (const float*)d_in[1];   // [8192, 64]
    float* out = (float*)d_out;

    // ws: stream [2 MB] | c0arr [32 KB] | cand_val [1 MB] | cand_idx [1 MB] | partials [4 KB]
    char*  bstream  = (char*)d_ws;
    float* c0arr    = (float*)(bstream + (size_t)NTILES * TILE_BYTES);
    float* cand_val = c0arr + N_EMB;
    int*   cand_idx = (int*)(cand_val + (size_t)NCHUNK * N_VOX);
    float* partials = (float*)(cand_idx + (size_t)NCHUNK * N_VOX);

    cbprep_kernel  <<<dim3(NTILES), dim3(256), 0, stream>>>(cb, bstream, c0arr);
    scan_kernel    <<<dim3((N_VOX / 256) * NCHUNK), dim3(512), 0, stream>>>(z, bstream, c0arr, cand_val, cand_idx);
    finalize_kernel<<<dim3(N_VOX * 8 / 256), dim3(256), 0, stream>>>(z, cb, cand_val, cand_idx, out, partials);
    loss_kernel    <<<1, 256, 0, stream>>>(partials, out);
}

// Round 9
// 190.167 us; speedup vs baseline: 1.0044x; 1.0044x over previous
//
#include <hip/hip_runtime.h>
#include <math.h>

#define N_VOX 32768
#define N_EMB 8192
#define DIM 64
#define NCHUNK 8
#define CODES_PER_CHUNK (N_EMB / NCHUNK)       // 1024
#define TILES_PER_CHUNK (CODES_PER_CHUNK / 32) // 32
#define NTILES (N_EMB / 32)                    // 256
#define TILE_BYTES 8192                        // bh[4x1KB] | bl[4x1KB]
#define CHUNK_BYTES (TILES_PER_CHUNK * TILE_BYTES)

typedef _Float16 half8 __attribute__((ext_vector_type(8)));
typedef float floatx4 __attribute__((ext_vector_type(4)));

#define FP16_MIN_NORMAL 6.1035156e-5f
#define LO_SCALE 2048.0f

// -------- kernel A: fused esq + B-fragment stream build (validated R9-R12) ---
// 256 thr/tile (thread = one (o,lane) slice). UNCHANGED layout:
// element (code n, k) lives at tile byte 512*(k>>3) + 16*n (+4096 for bl).
// c0arr[code] = -1024*esq.
__global__ __launch_bounds__(256) void cbprep_kernel(const float* __restrict__ cb,
                                                     char* __restrict__ stream,
                                                     float* __restrict__ c0arr) {
    __shared__ float red[256];
    int tid  = threadIdx.x;                      // 0..255
    int l    = tid & 63;
    int o    = tid >> 6;                         // K-chunk 0..3
    int m    = l & 31;
    int tile = blockIdx.x;                       // 0..255
    char* tbase = stream + (size_t)tile * TILE_BYTES;
    int code = tile * 32 + m;
    int kg   = l >> 5;

    const float* p = cb + (size_t)code * DIM + o * 16 + kg * 8;
    float ss = 0.f;
    half8 h, lo;
    #pragma unroll
    for (int j = 0; j < 8; ++j) {
        float x = p[j];
        ss = fmaf(x, x, ss);
        _Float16 hi = (_Float16)x;
        float hf = (float)hi;
        if (fabsf(hf) < FP16_MIN_NORMAL) { hi = (_Float16)0.f; hf = 0.f; }
        h[j]  = hi;
        lo[j] = (_Float16)((x - hf) * LO_SCALE);
    }
    *(half8*)(tbase +        o * 1024 + l * 16) = h;
    *(half8*)(tbase + 4096 + o * 1024 + l * 16) = lo;

    red[tid] = ss;
    __syncthreads();
    if (tid < 32) {                              // tid == m here
        float s = 0.f;
        #pragma unroll
        for (int q = 0; q < 8; ++q) s += red[tid + q * 32];
        c0arr[tile * 32 + tid] = -1024.0f * s;
    }
}

// -------- kernel B: MFMA argmin scan — R7 + anti-phase block stagger ---------
// R9: byte-identical compute to R7 (99.8µs: 8 waves/512thr, 32 rows/wave,
// 4 LDS buffers, counted-vmcnt 3-ahead, 16x16x32 with 4 independent MFMA
// chains, 64 VGPR) + ONE addition: a one-time per-block phase sleep.
// R7's PMC fits an in-phase-lock model: ~4 co-resident blocks/CU (grid =
// exact device capacity) barrier together -> all burst ds_reads together
// (LDS saturated 3072cyc, MFMA idle) then all MFMA together (3730cyc, LDS
// idle); 3072+3730 = 6800 =~ measured 7488cyc supercycle, MfmaUtil 50% =~
// measured 46.5%. Anti-phased quarters -> period max(3730,3072) -> ~90%.
// Stagger: co-resident blocks are blockIdx = b (mod 256) (XCD round-robin),
// so phase = (blockIdx>>8)&3, delay = phase * ~1920cyc (s_sleep(15) pairs),
// placed after prologue stage issue, before first sync. Different pipes in
// different phases => no contention force to re-lock; equal loop periods
// preserve the offset. Zero registers, zero numerics, zero reordering.
__global__ __launch_bounds__(512) void scan_kernel(const float* __restrict__ z,
                                                   const char* __restrict__ stream,
                                                   const float* __restrict__ c0arr,
                                                   float* __restrict__ cand_val,
                                                   int* __restrict__ cand_idx) {
    __shared__ __align__(16) char lds[4 * TILE_BYTES + CODES_PER_CHUNK * 4];
    float* c0_lds = (float*)(lds + 4 * TILE_BYTES);
    int tid   = threadIdx.x;
    int l     = tid & 63;
    int w     = tid >> 6;                        // wave 0..7
    int chunk = blockIdx.x & (NCHUNK - 1);
    int rg    = blockIdx.x >> 3;                 // 0..127, 256 rows per block
    int lr    = l & 15;                          // A row / B col within group
    int lq    = l >> 4;                          // quarter: k-octet / C row-quad
    int rowBase = rg * 256 + w * 32;             // wave's 32 rows

    // A fragments per (rowgroup r, khalf h): zh, zl = 2048*res, zhs = 2048*zh
    half8 zh[2][2], zl[2][2], zhs[2][2];
    #pragma unroll
    for (int r = 0; r < 2; ++r) {
        #pragma unroll
        for (int h = 0; h < 2; ++h) {
            const float* p = z + (size_t)(rowBase + r * 16 + lr) * DIM + h * 32 + lq * 8;
            #pragma unroll
            for (int j = 0; j < 8; ++j) {
                float x = p[j];
                _Float16 hi = (_Float16)x;
                float hf = (float)hi;
                if (fabsf(hf) < FP16_MIN_NORMAL) { hi = (_Float16)0.f; hf = 0.f; }
                zh[r][h][j] = hi;
                zl[r][h][j] = (_Float16)((x - hf) * LO_SCALE);
            }
            zhs[r][h] = zh[r][h] * (_Float16)2048.0f;
        }
    }

    const char*  sbase = stream + (size_t)chunk * CHUNK_BYTES;
    const float* c0p   = c0arr + chunk * CODES_PER_CHUNK;

    // best/bt position p = r*8 + c*4 + i  (row = rowBase+r*16+4*lq+i,
    // col-in-tile = c*16+lr)
    float best[16];
    int   bt[16];
    #pragma unroll
    for (int i = 0; i < 16; ++i) { best[i] = -3.4e38f; bt[i] = 0; }

    // stage one 8KB tile: wave w issues seg w (1KB, lane l -> +l*16)
#define STAGE(gt, lb)                                                              \
    do {                                                                           \
        const char* _g = (gt) + w * 1024 + l * 16;                                 \
        char*       _d = (lb) + w * 1024 + l * 16;                                 \
        __builtin_amdgcn_global_load_lds(                                          \
            (const __attribute__((address_space(1))) void*)_g,                     \
            (__attribute__((address_space(3))) void*)_d, 16, 0, 0);                \
    } while (0)

    // prologue: stage tiles 0..2 into bufs 0..2, fill c0 LDS
    STAGE(sbase,                          lds);
    STAGE(sbase + (size_t)TILE_BYTES,     lds + TILE_BYTES);
    STAGE(sbase + 2 * (size_t)TILE_BYTES, lds + 2 * TILE_BYTES);
    c0_lds[tid]       = c0p[tid];
    c0_lds[tid + 512] = c0p[tid + 512];

    // anti-phase stagger: co-resident blocks (b mod 256) get phases 0..3,
    // each ~1920cyc apart (s_sleep(15) =~ 960cyc). One-time cost <= 2.4us.
    {
        int ph = (blockIdx.x >> 8) & 3;
        for (int i = 0; i < ph; ++i) {
            __builtin_amdgcn_s_sleep(15);
            __builtin_amdgcn_s_sleep(15);
        }
    }
    __syncthreads();                             // drains vmcnt to 0 (once)

    for (int t = 0; t < TILES_PER_CHUNK; ++t) {
        if (t < TILES_PER_CHUNK - 2)
            asm volatile("s_waitcnt vmcnt(2)" ::: "memory");
        else if (t == TILES_PER_CHUNK - 2)
            asm volatile("s_waitcnt vmcnt(1)" ::: "memory");
        else
            asm volatile("s_waitcnt vmcnt(0)" ::: "memory");
        __builtin_amdgcn_s_barrier();            // all waves: stage t landed
        asm volatile("" ::: "memory");           // pin ds_reads below barrier

        if (t + 3 < TILES_PER_CHUNK)             // overwrites buf[(t-1)&3]
            STAGE(sbase + (size_t)(t + 3) * TILE_BYTES,
                  lds + ((t + 3) & 3) * TILE_BYTES);

        const char* lb = lds + (t & 3) * TILE_BYTES;
        const char* bp = lb + 512 * lq + 16 * lr;
        half8 bh00 = *(const half8*)(bp +    0);         // c=0, h=0
        half8 bh10 = *(const half8*)(bp +  256);         // c=1, h=0
        half8 bh01 = *(const half8*)(bp + 2048);         // c=0, h=1
        half8 bh11 = *(const half8*)(bp + 2304);         // c=1, h=1
        half8 bl00 = *(const half8*)(bp + 4096);
        half8 bl10 = *(const half8*)(bp + 4352);
        half8 bl01 = *(const half8*)(bp + 6144);
        half8 bl11 = *(const half8*)(bp + 6400);
        float c00 = c0_lds[t * 32 + lr];                 // colgroup 0
        float c01 = c0_lds[t * 32 + 16 + lr];            // colgroup 1

        floatx4 a00 = {c00, c00, c00, c00};              // [r=0][c=0]
        floatx4 a01 = {c01, c01, c01, c01};              // [r=0][c=1]
        floatx4 a10 = {c00, c00, c00, c00};              // [r=1][c=0]
        floatx4 a11 = {c01, c01, c01, c01};              // [r=1][c=1]

        // 4 independent 6-deep chains, interleaved (ILP=4)
        __builtin_amdgcn_s_setprio(1);
        a00 = __builtin_amdgcn_mfma_f32_16x16x32_f16(zhs[0][0], bh00, a00, 0, 0, 0);
        a01 = __builtin_amdgcn_mfma_f32_16x16x32_f16(zhs[0][0], bh10, a01, 0, 0, 0);
        a10 = __builtin_amdgcn_mfma_f32_16x16x32_f16(zhs[1][0], bh00, a10, 0, 0, 0);
        a11 = __builtin_amdgcn_mfma_f32_16x16x32_f16(zhs[1][0], bh10, a11, 0, 0, 0);
        a00 = __builtin_amdgcn_mfma_f32_16x16x32_f16(zl[0][0],  bh00, a00, 0, 0, 0);
        a01 = __builtin_amdgcn_mfma_f32_16x16x32_f16(zl[0][0],  bh10, a01, 0, 0, 0);
        a10 = __builtin_amdgcn_mfma_f32_16x16x32_f16(zl[1][0],  bh00, a10, 0, 0, 0);
        a11 = __builtin_amdgcn_mfma_f32_16x16x32_f16(zl[1][0],  bh10, a11, 0, 0, 0);
        a00 = __builtin_amdgcn_mfma_f32_16x16x32_f16(zh[0][0],  bl00, a00, 0, 0, 0);
        a01 = __builtin_amdgcn_mfma_f32_16x16x32_f16(zh[0][0],  bl10, a01, 0, 0, 0);
        a10 = __builtin_amdgcn_mfma_f32_16x16x32_f16(zh[1][0],  bl00, a10, 0, 0, 0);
        a11 = __builtin_amdgcn_mfma_f32_16x16x32_f16(zh[1][0],  bl10, a11, 0, 0, 0);
        a00 = __builtin_amdgcn_mfma_f32_16x16x32_f16(zhs[0][1], bh01, a00, 0, 0, 0);
        a01 = __builtin_amdgcn_mfma_f32_16x16x32_f16(zhs[0][1], bh11, a01, 0, 0, 0);
        a10 = __builtin_amdgcn_mfma_f32_16x16x32_f16(zhs[1][1], bh01, a10, 0, 0, 0);
        a11 = __builtin_amdgcn_mfma_f32_16x16x32_f16(zhs[1][1], bh11, a11, 0, 0, 0);
        a00 = __builtin_amdgcn_mfma_f32_16x16x32_f16(zl[0][1],  bh01, a00, 0, 0, 0);
        a01 = __builtin_amdgcn_mfma_f32_16x16x32_f16(zl[0][1],  bh11, a01, 0, 0, 0);
        a10 = __builtin_amdgcn_mfma_f32_16x16x32_f16(zl[1][1],  bh01, a10, 0, 0, 0);
        a11 = __builtin_amdgcn_mfma_f32_16x16x32_f16(zl[1][1],  bh11, a11, 0, 0, 0);
        a00 = __builtin_amdgcn_mfma_f32_16x16x32_f16(zh[0][1],  bl01, a00, 0, 0, 0);
        a01 = __builtin_amdgcn_mfma_f32_16x16x32_f16(zh[0][1],  bl11, a01, 0, 0, 0);
        a10 = __builtin_amdgcn_mfma_f32_16x16x32_f16(zh[1][1],  bl01, a10, 0, 0, 0);
        a11 = __builtin_amdgcn_mfma_f32_16x16x32_f16(zh[1][1],  bl11, a11, 0, 0, 0);
        __builtin_amdgcn_s_setprio(0);

        #pragma unroll
        for (int i = 0; i < 4; ++i) {
            if (a00[i] > best[ 0 + i]) { best[ 0 + i] = a00[i]; bt[ 0 + i] = t; }
            if (a01[i] > best[ 4 + i]) { best[ 4 + i] = a01[i]; bt[ 4 + i] = t; }
            if (a10[i] > best[ 8 + i]) { best[ 8 + i] = a10[i]; bt[ 8 + i] = t; }
            if (a11[i] > best[12 + i]) { best[12 + i] = a11[i]; bt[12 + i] = t; }
        }
    }
#undef STAGE

    // Epilogue: in-lane colgroup merge, then 4-step shuffle argmax over the
    // 16 cols (lane bits 0..3). Tie -> lower within-chunk id (tournament on
    // (v desc, id asc) — order-independent, same semantics as validated).
    #pragma unroll
    for (int r = 0; r < 2; ++r) {
        #pragma unroll
        for (int i = 0; i < 4; ++i) {
            float v0 = best[r * 8 + i];     int id0 = bt[r * 8 + i] * 32 + lr;
            float v1 = best[r * 8 + 4 + i]; int id1 = bt[r * 8 + 4 + i] * 32 + 16 + lr;
            float v = v0; int id = id0;
            if (v1 > v || (v1 == v && id1 < id)) { v = v1; id = id1; }
            #pragma unroll
            for (int off = 1; off < 16; off <<= 1) {
                float ov = __shfl_xor(v, off, 64);
                int   oi = __shfl_xor(id, off, 64);
                if (ov > v || (ov == v && oi < id)) { v = ov; id = oi; }
            }
            if (lr == 0) {
                int row = rowBase + r * 16 + 4 * lq + i;
                cand_val[chunk * N_VOX + row] = v;
                cand_idx[chunk * N_VOX + row] = chunk * CODES_PER_CHUNK + id;
            }
        }
    }
}

// -------- kernel C: pick max stored score + gather (no re-score) -------------
// 8 lanes per row: lane c reads chunk c's (val, idx); width-8 shuffle argmax
// (tie -> lower id) — identical ordering semantics to scan's within-chunk
// reduce, so cross-chunk pick is consistent with the validated pipeline.
__global__ __launch_bounds__(256) void finalize_kernel(const float* __restrict__ z,
                                                       const float* __restrict__ cb,
                                                       const float* __restrict__ cand_val,
                                                       const int* __restrict__ cand_idx,
                                                       float* __restrict__ out,
                                                       float* __restrict__ partials) {
    int g    = blockIdx.x * 256 + threadIdx.x;
    int row  = g >> 3;
    int c    = g & 7;                  // chunk / candidate 0..7

    float v  = cand_val[c * N_VOX + row];
    int   id = cand_idx[c * N_VOX + row];
    #pragma unroll
    for (int off = 1; off < 8; off <<= 1) {
        float ov = __shfl_xor(v, off, 8);
        int   oi = __shfl_xor(id, off, 8);
        if (ov > v || (ov == v && oi < id)) { v = ov; id = oi; }
    }
    // all 8 lanes hold the winning id for this row

    if (c == 0)
        out[(size_t)N_VOX * DIM + 2 + row] = (float)id;

    // cooperative gather+write: lane handles elements [c*8, c*8+8)
    const float4* zp = (const float4*)(z  + (size_t)row * DIM + c * 8);
    const float4* qp = (const float4*)(cb + (size_t)id  * DIM + c * 8);
    float4*       op = (float4*)(out + (size_t)row * DIM + c * 8);
    float ss = 0.f;
    #pragma unroll
    for (int d = 0; d < 2; ++d) {
        float4 zt = zp[d], qt = qp[d];
        float dx = qt.x - zt.x, dy = qt.y - zt.y;
        float dz = qt.z - zt.z, dw = qt.w - zt.w;
        float4 o;
        o.x = zt.x + dx; o.y = zt.y + dy;   // mirrors reference z + (q - z)
        o.z = zt.z + dz; o.w = zt.w + dw;
        op[d] = o;
        ss += dx*dx + dy*dy + dz*dz + dw*dw;
    }

    __shared__ float red[256];
    red[threadIdx.x] = ss;
    __syncthreads();
    #pragma unroll
    for (int s = 128; s > 0; s >>= 1) {
        if (threadIdx.x < s) red[threadIdx.x] += red[threadIdx.x + s];
        __syncthreads();
    }
    if (threadIdx.x == 0) partials[blockIdx.x] = red[0];
}

// -------- kernel D: reduce 1024 partials -> both losses --------
__global__ __launch_bounds__(256) void loss_kernel(const float* __restrict__ partials,
                                                   float* __restrict__ out) {
    __shared__ float red[256];
    red[threadIdx.x] = (partials[threadIdx.x]       + partials[threadIdx.x + 256])
                     + (partials[threadIdx.x + 512] + partials[threadIdx.x + 768]);
    __syncthreads();
    #pragma unroll
    for (int st = 128; st > 0; st >>= 1) {
        if (threadIdx.x < st) red[threadIdx.x] += red[threadIdx.x + st];
        __syncthreads();
    }
    if (threadIdx.x == 0) {
        float mean = red[0] / (float)((size_t)N_VOX * DIM);
        out[(size_t)N_VOX * DIM + 0] = mean;
        out[(size_t)N_VOX * DIM + 1] = mean;
    }
}

extern "C" void kernel_launch(void* const* d_in, const int* in_sizes, int n_in,
                              void* d_out, int out_size, void* d_ws, size_t ws_size,
                              hipStream_t stream) {
    const float* z  = (const float*)d_in[0];   // [32768, 64]
    const float* cb = (const float*)d_in[1];   // [8192, 64]
    float* out = (float*)d_out;

    // ws: stream [2 MB] | c0arr [32 KB] | cand_val [1 MB] | cand_idx [1 MB] | partials [4 KB]
    char*  bstream  = (char*)d_ws;
    float* c0arr    = (float*)(bstream + (size_t)NTILES * TILE_BYTES);
    float* cand_val = c0arr + N_EMB;
    int*   cand_idx = (int*)(cand_val + (size_t)NCHUNK * N_VOX);
    float* partials = (float*)(cand_idx + (size_t)NCHUNK * N_VOX);

    cbprep_kernel  <<<dim3(NTILES), dim3(256), 0, stream>>>(cb, bstream, c0arr);
    scan_kernel    <<<dim3((N_VOX / 256) * NCHUNK), dim3(512), 0, stream>>>(z, bstream, c0arr, cand_val, cand_idx);
    finalize_kernel<<<dim3(N_VOX * 8 / 256), dim3(256), 0, stream>>>(z, cb, cand_val, cand_idx, out, partials);
    loss_kernel    <<<1, 256, 0, stream>>>(partials, out);
}

// Round 10
// 174.283 us; speedup vs baseline: 1.0960x; 1.0911x over previous
//
#include <hip/hip_runtime.h>
#include <math.h>

#define N_VOX 32768
#define N_EMB 8192
#define DIM 64
#define NCHUNK 8
#define CODES_PER_CHUNK (N_EMB / NCHUNK)       // 1024
#define TILES_PER_CHUNK (CODES_PER_CHUNK / 32) // 32
#define NTILES (N_EMB / 32)                    // 256
#define TILE_BYTES 8192                        // bh[4x1KB] | bl[4x1KB]
#define CHUNK_BYTES (TILES_PER_CHUNK * TILE_BYTES)

typedef _Float16 half8 __attribute__((ext_vector_type(8)));
typedef float floatx4 __attribute__((ext_vector_type(4)));

#define FP16_MIN_NORMAL 6.1035156e-5f
#define LO_SCALE 2048.0f

// -------- kernel A: fused esq + B-fragment stream build (validated R9-R12) ---
// 256 thr/tile (thread = one (o,lane) slice). UNCHANGED layout:
// element (code n, k) lives at tile byte 512*(k>>3) + 16*n (+4096 for bl).
// c0arr[code] = -1024*esq.
__global__ __launch_bounds__(256) void cbprep_kernel(const float* __restrict__ cb,
                                                     char* __restrict__ stream,
                                                     float* __restrict__ c0arr) {
    __shared__ float red[256];
    int tid  = threadIdx.x;                      // 0..255
    int l    = tid & 63;
    int o    = tid >> 6;                         // K-chunk 0..3
    int m    = l & 31;
    int tile = blockIdx.x;                       // 0..255
    char* tbase = stream + (size_t)tile * TILE_BYTES;
    int code = tile * 32 + m;
    int kg   = l >> 5;

    const float* p = cb + (size_t)code * DIM + o * 16 + kg * 8;
    float ss = 0.f;
    half8 h, lo;
    #pragma unroll
    for (int j = 0; j < 8; ++j) {
        float x = p[j];
        ss = fmaf(x, x, ss);
        _Float16 hi = (_Float16)x;
        float hf = (float)hi;
        if (fabsf(hf) < FP16_MIN_NORMAL) { hi = (_Float16)0.f; hf = 0.f; }
        h[j]  = hi;
        lo[j] = (_Float16)((x - hf) * LO_SCALE);
    }
    *(half8*)(tbase +        o * 1024 + l * 16) = h;
    *(half8*)(tbase + 4096 + o * 1024 + l * 16) = lo;

    red[tid] = ss;
    __syncthreads();
    if (tid < 32) {                              // tid == m here
        float s = 0.f;
        #pragma unroll
        for (int q = 0; q < 8; ++q) s += red[tid + q * 32];
        c0arr[tile * 32 + tid] = -1024.0f * s;
    }
}

// -------- kernel B: MFMA argmin scan — NO LDS, NO barriers (L2-direct B) -----
// R10: R7's compute (16x16x32, 4 independent MFMA chains, identical math/
// mapping/tie-break) with the LDS staging pipeline DELETED. Rationale
// (guide Common-mistake #7): the chunk stream is 256KB = L2-resident, and
// all 8 waves of a block read the same 8KB tile (first wave L2->L1, rest
// L1-hit), so the global->LDS hop bought nothing except the per-tile
// block barrier — which phase-locked the ~3 resident waves/SIMD into
// alternating LDS-burst/MFMA-burst (MfmaUtil capped ~46%). B-fragments
// and c0 now load straight to registers from global; no __syncthreads,
// no s_waitcnt asm, no STAGE. Waves free-run and self-de-phase: one
// wave's VMEM wait overlaps the others' MFMA. #pragma unroll 2 lets the
// scheduler issue tile t+1's loads under tile t's MFMAs.
// Mappings (guide m89/m121): A/B idx=l&15, k=(l>>4)*8+j; C/D col=l&15,
// row=4*(l>>4)+reg. acc = 2048*(dot - esq/2) = c0 + zhs*bh + zl*bh + zh*bl.
// Maximize, tie -> lower within-chunk id (order-independent tournament).
__global__ __launch_bounds__(512) void scan_kernel(const float* __restrict__ z,
                                                   const char* __restrict__ stream,
                                                   const float* __restrict__ c0arr,
                                                   float* __restrict__ cand_val,
                                                   int* __restrict__ cand_idx) {
    int tid   = threadIdx.x;
    int l     = tid & 63;
    int w     = tid >> 6;                        // wave 0..7
    int chunk = blockIdx.x & (NCHUNK - 1);
    int rg    = blockIdx.x >> 3;                 // 0..127, 256 rows per block
    int lr    = l & 15;                          // A row / B col within group
    int lq    = l >> 4;                          // quarter: k-octet / C row-quad
    int rowBase = rg * 256 + w * 32;             // wave's 32 rows

    // A fragments per (rowgroup r, khalf h): zh, zl = 2048*res, zhs = 2048*zh
    half8 zh[2][2], zl[2][2], zhs[2][2];
    #pragma unroll
    for (int r = 0; r < 2; ++r) {
        #pragma unroll
        for (int h = 0; h < 2; ++h) {
            const float* p = z + (size_t)(rowBase + r * 16 + lr) * DIM + h * 32 + lq * 8;
            #pragma unroll
            for (int j = 0; j < 8; ++j) {
                float x = p[j];
                _Float16 hi = (_Float16)x;
                float hf = (float)hi;
                if (fabsf(hf) < FP16_MIN_NORMAL) { hi = (_Float16)0.f; hf = 0.f; }
                zh[r][h][j] = hi;
                zl[r][h][j] = (_Float16)((x - hf) * LO_SCALE);
            }
            zhs[r][h] = zh[r][h] * (_Float16)2048.0f;
        }
    }

    const char*  sbase = stream + (size_t)chunk * CHUNK_BYTES;
    const float* c0p   = c0arr + chunk * CODES_PER_CHUNK;
    int boff = 512 * lq + 16 * lr;               // per-lane byte off in tile

    // best/bt position p = r*8 + c*4 + i  (row = rowBase+r*16+4*lq+i,
    // col-in-tile = c*16+lr)
    float best[16];
    int   bt[16];
    #pragma unroll
    for (int i = 0; i < 16; ++i) { best[i] = -3.4e38f; bt[i] = 0; }

    #pragma unroll 2
    for (int t = 0; t < TILES_PER_CHUNK; ++t) {
        const char* bp = sbase + (size_t)t * TILE_BYTES + boff;
        half8 bh00 = *(const half8*)(bp +    0);         // c=0, h=0
        half8 bh10 = *(const half8*)(bp +  256);         // c=1, h=0
        half8 bh01 = *(const half8*)(bp + 2048);         // c=0, h=1
        half8 bh11 = *(const half8*)(bp + 2304);         // c=1, h=1
        half8 bl00 = *(const half8*)(bp + 4096);
        half8 bl10 = *(const half8*)(bp + 4352);
        half8 bl01 = *(const half8*)(bp + 6144);
        half8 bl11 = *(const half8*)(bp + 6400);
        float c00  = c0p[t * 32 + lr];                   // colgroup 0
        float c01  = c0p[t * 32 + 16 + lr];              // colgroup 1

        floatx4 a00 = {c00, c00, c00, c00};              // [r=0][c=0]
        floatx4 a01 = {c01, c01, c01, c01};              // [r=0][c=1]
        floatx4 a10 = {c00, c00, c00, c00};              // [r=1][c=0]
        floatx4 a11 = {c01, c01, c01, c01};              // [r=1][c=1]

        // 4 independent 6-deep chains, interleaved (ILP=4)
        __builtin_amdgcn_s_setprio(1);
        a00 = __builtin_amdgcn_mfma_f32_16x16x32_f16(zhs[0][0], bh00, a00, 0, 0, 0);
        a01 = __builtin_amdgcn_mfma_f32_16x16x32_f16(zhs[0][0], bh10, a01, 0, 0, 0);
        a10 = __builtin_amdgcn_mfma_f32_16x16x32_f16(zhs[1][0], bh00, a10, 0, 0, 0);
        a11 = __builtin_amdgcn_mfma_f32_16x16x32_f16(zhs[1][0], bh10, a11, 0, 0, 0);
        a00 = __builtin_amdgcn_mfma_f32_16x16x32_f16(zl[0][0],  bh00, a00, 0, 0, 0);
        a01 = __builtin_amdgcn_mfma_f32_16x16x32_f16(zl[0][0],  bh10, a01, 0, 0, 0);
        a10 = __builtin_amdgcn_mfma_f32_16x16x32_f16(zl[1][0],  bh00, a10, 0, 0, 0);
        a11 = __builtin_amdgcn_mfma_f32_16x16x32_f16(zl[1][0],  bh10, a11, 0, 0, 0);
        a00 = __builtin_amdgcn_mfma_f32_16x16x32_f16(zh[0][0],  bl00, a00, 0, 0, 0);
        a01 = __builtin_amdgcn_mfma_f32_16x16x32_f16(zh[0][0],  bl10, a01, 0, 0, 0);
        a10 = __builtin_amdgcn_mfma_f32_16x16x32_f16(zh[1][0],  bl00, a10, 0, 0, 0);
        a11 = __builtin_amdgcn_mfma_f32_16x16x32_f16(zh[1][0],  bl10, a11, 0, 0, 0);
        a00 = __builtin_amdgcn_mfma_f32_16x16x32_f16(zhs[0][1], bh01, a00, 0, 0, 0);
        a01 = __builtin_amdgcn_mfma_f32_16x16x32_f16(zhs[0][1], bh11, a01, 0, 0, 0);
        a10 = __builtin_amdgcn_mfma_f32_16x16x32_f16(zhs[1][1], bh01, a10, 0, 0, 0);
        a11 = __builtin_amdgcn_mfma_f32_16x16x32_f16(zhs[1][1], bh11, a11, 0, 0, 0);
        a00 = __builtin_amdgcn_mfma_f32_16x16x32_f16(zl[0][1],  bh01, a00, 0, 0, 0);
        a01 = __builtin_amdgcn_mfma_f32_16x16x32_f16(zl[0][1],  bh11, a01, 0, 0, 0);
        a10 = __builtin_amdgcn_mfma_f32_16x16x32_f16(zl[1][1],  bh01, a10, 0, 0, 0);
        a11 = __builtin_amdgcn_mfma_f32_16x16x32_f16(zl[1][1],  bh11, a11, 0, 0, 0);
        a00 = __builtin_amdgcn_mfma_f32_16x16x32_f16(zh[0][1],  bl01, a00, 0, 0, 0);
        a01 = __builtin_amdgcn_mfma_f32_16x16x32_f16(zh[0][1],  bl11, a01, 0, 0, 0);
        a10 = __builtin_amdgcn_mfma_f32_16x16x32_f16(zh[1][1],  bl01, a10, 0, 0, 0);
        a11 = __builtin_amdgcn_mfma_f32_16x16x32_f16(zh[1][1],  bl11, a11, 0, 0, 0);
        __builtin_amdgcn_s_setprio(0);

        #pragma unroll
        for (int i = 0; i < 4; ++i) {
            if (a00[i] > best[ 0 + i]) { best[ 0 + i] = a00[i]; bt[ 0 + i] = t; }
            if (a01[i] > best[ 4 + i]) { best[ 4 + i] = a01[i]; bt[ 4 + i] = t; }
            if (a10[i] > best[ 8 + i]) { best[ 8 + i] = a10[i]; bt[ 8 + i] = t; }
            if (a11[i] > best[12 + i]) { best[12 + i] = a11[i]; bt[12 + i] = t; }
        }
    }

    // Epilogue: in-lane colgroup merge, then 4-step shuffle argmax over the
    // 16 cols (lane bits 0..3). Tie -> lower within-chunk id (tournament on
    // (v desc, id asc) — order-independent, same semantics as validated).
    #pragma unroll
    for (int r = 0; r < 2; ++r) {
        #pragma unroll
        for (int i = 0; i < 4; ++i) {
            float v0 = best[r * 8 + i];     int id0 = bt[r * 8 + i] * 32 + lr;
            float v1 = best[r * 8 + 4 + i]; int id1 = bt[r * 8 + 4 + i] * 32 + 16 + lr;
            float v = v0; int id = id0;
            if (v1 > v || (v1 == v && id1 < id)) { v = v1; id = id1; }
            #pragma unroll
            for (int off = 1; off < 16; off <<= 1) {
                float ov = __shfl_xor(v, off, 64);
                int   oi = __shfl_xor(id, off, 64);
                if (ov > v || (ov == v && oi < id)) { v = ov; id = oi; }
            }
            if (lr == 0) {
                int row = rowBase + r * 16 + 4 * lq + i;
                cand_val[chunk * N_VOX + row] = v;
                cand_idx[chunk * N_VOX + row] = chunk * CODES_PER_CHUNK + id;
            }
        }
    }
}

// -------- kernel C: pick max stored score + gather (no re-score) -------------
// 8 lanes per row: lane c reads chunk c's (val, idx); width-8 shuffle argmax
// (tie -> lower id) — identical ordering semantics to scan's within-chunk
// reduce, so cross-chunk pick is consistent with the validated pipeline.
__global__ __launch_bounds__(256) void finalize_kernel(const float* __restrict__ z,
                                                       const float* __restrict__ cb,
                                                       const float* __restrict__ cand_val,
                                                       const int* __restrict__ cand_idx,
                                                       float* __restrict__ out,
                                                       float* __restrict__ partials) {
    int g    = blockIdx.x * 256 + threadIdx.x;
    int row  = g >> 3;
    int c    = g & 7;                  // chunk / candidate 0..7

    float v  = cand_val[c * N_VOX + row];
    int   id = cand_idx[c * N_VOX + row];
    #pragma unroll
    for (int off = 1; off < 8; off <<= 1) {
        float ov = __shfl_xor(v, off, 8);
        int   oi = __shfl_xor(id, off, 8);
        if (ov > v || (ov == v && oi < id)) { v = ov; id = oi; }
    }
    // all 8 lanes hold the winning id for this row

    if (c == 0)
        out[(size_t)N_VOX * DIM + 2 + row] = (float)id;

    // cooperative gather+write: lane handles elements [c*8, c*8+8)
    const float4* zp = (const float4*)(z  + (size_t)row * DIM + c * 8);
    const float4* qp = (const float4*)(cb + (size_t)id  * DIM + c * 8);
    float4*       op = (float4*)(out + (size_t)row * DIM + c * 8);
    float ss = 0.f;
    #pragma unroll
    for (int d = 0; d < 2; ++d) {
        float4 zt = zp[d], qt = qp[d];
        float dx = qt.x - zt.x, dy = qt.y - zt.y;
        float dz = qt.z - zt.z, dw = qt.w - zt.w;
        float4 o;
        o.x = zt.x + dx; o.y = zt.y + dy;   // mirrors reference z + (q - z)
        o.z = zt.z + dz; o.w = zt.w + dw;
        op[d] = o;
        ss += dx*dx + dy*dy + dz*dz + dw*dw;
    }

    __shared__ float red[256];
    red[threadIdx.x] = ss;
    __syncthreads();
    #pragma unroll
    for (int s = 128; s > 0; s >>= 1) {
        if (threadIdx.x < s) red[threadIdx.x] += red[threadIdx.x + s];
        __syncthreads();
    }
    if (threadIdx.x == 0) partials[blockIdx.x] = red[0];
}

// -------- kernel D: reduce 1024 partials -> both losses --------
__global__ __launch_bounds__(256) void loss_kernel(const float* __restrict__ partials,
                                                   float* __restrict__ out) {
    __shared__ float red[256];
    red[threadIdx.x] = (partials[threadIdx.x]       + partials[threadIdx.x + 256])
                     + (partials[threadIdx.x + 512] + partials[threadIdx.x + 768]);
    __syncthreads();
    #pragma unroll
    for (int st = 128; st > 0; st >>= 1) {
        if (threadIdx.x < st) red[threadIdx.x] += red[threadIdx.x + st];
        __syncthreads();
    }
    if (threadIdx.x == 0) {
        float mean = red[0] / (float)((size_t)N_VOX * DIM);
        out[(size_t)N_VOX * DIM + 0] = mean;
        out[(size_t)N_VOX * DIM + 1] = mean;
    }
}

extern "C" void kernel_launch(void* const* d_in, const int* in_sizes, int n_in,
                              void* d_out, int out_size, void* d_ws, size_t ws_size,
                              hipStream_t stream) {
    const float* z  = (const float*)d_in[0];   // [32768, 64]
    const float* cb = (const float*)d_in[1];   // [8192, 64]
    float* out = (float*)d_out;

    // ws: stream [2 MB] | c0arr [32 KB] | cand_val [1 MB] | cand_idx [1 MB] | partials [4 KB]
    char*  bstream  = (char*)d_ws;
    float* c0arr    = (float*)(bstream + (size_t)NTILES * TILE_BYTES);
    float* cand_val = c0arr + N_EMB;
    int*   cand_idx = (int*)(cand_val + (size_t)NCHUNK * N_VOX);
    float* partials = (float*)(cand_idx + (size_t)NCHUNK * N_VOX);

    cbprep_kernel  <<<dim3(NTILES), dim3(256), 0, stream>>>(cb, bstream, c0arr);
    scan_kernel    <<<dim3((N_VOX / 256) * NCHUNK), dim3(512), 0, stream>>>(z, bstream, c0arr, cand_val, cand_idx);
    finalize_kernel<<<dim3(N_VOX * 8 / 256), dim3(256), 0, stream>>>(z, cb, cand_val, cand_idx, out, partials);
    loss_kernel    <<<1, 256, 0, stream>>>(partials, out);
}